// Round 1
// baseline (185.910 us; speedup 1.0000x reference)
//
#include <hip/hip_runtime.h>

#define NQ 12
#define NL 4
#define NGATES (NQ * NL)

// ---------------------------------------------------------------------------
// Compile-time circuit compilation.
// Physical index p = (lane << 6) | r  (12 bits). Logical amplitude psi[y] is
// stored at p = L*y (L linear over GF(2), starts as identity).
// - RX on logical bit b pairs physical p with p ^ col_b(L). RX is symmetric,
//   so each element updates as: new = c*old - i*s*partner (no side needed).
// - CNOT(cb -> tb) updates L only: col[cb] ^= col[tb]. No data movement.
// - <Z_b> sign at p = (-1)^parity(p & row_b(L^-1)).
// Qubit w <-> logical bit (11 - w)  [reference reshape puts qubit 0 at MSB].
// ---------------------------------------------------------------------------
struct Masks { unsigned rx[NGATES]; unsigned z[NQ]; };

constexpr Masks compute_masks() {
  Masks mk{};
  unsigned col[NQ] = {};
  for (int b = 0; b < NQ; ++b) col[b] = 1u << b;
  int g = 0;
  for (int l = 0; l < NL; ++l) {
    for (int w = 0; w < NQ; ++w) mk.rx[g++] = col[NQ - 1 - w];
    for (int i = 0; i < NQ; ++i) {           // ring CNOT(i, (i+1)%12)
      int cb = NQ - 1 - i;
      int tb = NQ - 1 - ((i + 1) % NQ);
      col[cb] ^= col[tb];
    }
  }
  // Invert final L (rows) over GF(2) for the Z-parity masks.
  unsigned A[NQ] = {}, Inv[NQ] = {};
  for (int i = 0; i < NQ; ++i) {
    unsigned rowv = 0;
    for (int j = 0; j < NQ; ++j) rowv |= ((col[j] >> i) & 1u) << j;
    A[i] = rowv;
    Inv[i] = 1u << i;
  }
  for (int c = 0; c < NQ; ++c) {
    int piv = c;
    while (((A[piv] >> c) & 1u) == 0u) ++piv;
    unsigned ta = A[piv]; A[piv] = A[c]; A[c] = ta;
    unsigned ti = Inv[piv]; Inv[piv] = Inv[c]; Inv[c] = ti;
    for (int r = 0; r < NQ; ++r)
      if (r != c && ((A[r] >> c) & 1u)) { A[r] ^= A[c]; Inv[r] ^= Inv[c]; }
  }
  for (int w = 0; w < NQ; ++w) mk.z[w] = Inv[NQ - 1 - w];
  return mk;
}

constexpr Masks MK = compute_masks();

__device__ __forceinline__ float shflx(float v, int m) { return __shfl_xor(v, m, 64); }

// RX with XOR-mask: mr = in-register bits, ml = cross-lane bits.
// new[p] = c*old[p] - i*s*old[p^m]  =>  re' = c*re + s*p.im ; im' = c*im - s*p.re
template <int G>
__device__ __forceinline__ void apply_gate(float (&re)[64], float (&im)[64],
                                           float c, float s) {
  constexpr unsigned m = MK.rx[G];
  constexpr int mr = (int)(m & 63u);
  constexpr int ml = (int)((m >> 6) & 63u);
  if constexpr (ml == 0) {
    // pure in-register pairing
#pragma unroll
    for (int r = 0; r < 64; ++r) {
      const int r2 = r ^ mr;
      if (r < r2) {
        float ar = re[r], ai = im[r], br = re[r2], bi = im[r2];
        re[r]  = fmaf(s, bi, c * ar);
        im[r]  = fmaf(-s, br, c * ai);
        re[r2] = fmaf(s, ai, c * br);
        im[r2] = fmaf(-s, ar, c * bi);
      }
    }
  } else if constexpr (mr == 0) {
    // pure cross-lane pairing (same register index on partner lane)
#pragma unroll
    for (int r = 0; r < 64; ++r) {
      float pr_ = shflx(re[r], ml);
      float pi_ = shflx(im[r], ml);
      re[r] = fmaf(s, pi_, c * re[r]);
      im[r] = fmaf(-s, pr_, c * im[r]);
    }
  } else {
    // mixed: partner is register r^mr on lane^ml; process register pairs
#pragma unroll
    for (int r = 0; r < 64; ++r) {
      const int r2 = r ^ mr;
      if (r < r2) {
        float p1r = shflx(re[r2], ml);
        float p1i = shflx(im[r2], ml);
        float p2r = shflx(re[r], ml);
        float p2i = shflx(im[r], ml);
        re[r]  = fmaf(s, p1i, c * re[r]);
        im[r]  = fmaf(-s, p1r, c * im[r]);
        re[r2] = fmaf(s, p2i, c * re[r2]);
        im[r2] = fmaf(-s, p2r, c * im[r2]);
      }
    }
  }
}

template <int G>
__device__ __forceinline__ void run_gates(float (&re)[64], float (&im)[64],
                                          const float* __restrict__ wts) {
  if constexpr (G < NGATES) {
    float s, c;
    __sincosf(wts[G] * 0.5f, &s, &c);   // wts flat (NL,NQ) row-major == gate order
    apply_gate<G>(re, im, c, s);
    run_gates<G + 1>(re, im, wts);
  }
}

template <int W>
__device__ __forceinline__ void expvals(const float (&a2)[64], int lane,
                                        float* __restrict__ outp) {
  if constexpr (W < NQ) {
    constexpr unsigned zm = MK.z[W];
    constexpr int zr = (int)(zm & 63u);
    constexpr int zl = (int)((zm >> 6) & 63u);
    float acc = 0.f;
#pragma unroll
    for (int r = 0; r < 64; ++r) {
      if (__builtin_popcount((unsigned)(r & zr)) & 1) acc -= a2[r];
      else                                            acc += a2[r];
    }
    if (__popc(lane & zl) & 1) acc = -acc;
#pragma unroll
    for (int off = 32; off >= 1; off >>= 1) acc += shflx(acc, off);
    if (lane == 0) outp[W] = acc;
    expvals<W + 1>(a2, lane, outp);
  }
}

__global__ __launch_bounds__(256, 2) void qsim_kernel(
    const float* __restrict__ x, const float* __restrict__ wts,
    float* __restrict__ out) {
  const int bidx = (blockIdx.x << 2) + (threadIdx.x >> 6);  // one wave per batch elem
  const int lane = threadIdx.x & 63;

  // x row: 12 floats, 48B-aligned offset -> three float4 loads (broadcast across lanes)
  const float4* xv = reinterpret_cast<const float4*>(x + bidx * NQ);
  float4 q0 = xv[0], q1 = xv[1], q2 = xv[2];
  const float xa[NQ] = {q0.x, q0.y, q0.z, q0.w, q1.x, q1.y, q1.z, q1.w,
                        q2.x, q2.y, q2.z, q2.w};

  float cx[NQ], sx[NQ];
#pragma unroll
  for (int w = 0; w < NQ; ++w) __sincosf(xa[w] * 0.5f, &sx[w], &cx[w]);

  // Initial product state after the RY layer (all real).
  // lane bits 5..0 = qubits 0..5 ; register bits 5..0 = qubits 6..11
  float lp = 1.f;
#pragma unroll
  for (int w = 0; w < 6; ++w) lp *= ((lane >> (5 - w)) & 1) ? sx[w] : cx[w];

  float re[64], im[64];
  re[0] = lp;
#pragma unroll
  for (int step = 0; step < 6; ++step) {   // recursive doubling over reg bits
    const int w = 11 - step;               // qubit w sits at reg bit `step`
#pragma unroll
    for (int k = 0; k < 64; ++k) {
      if (k < (1 << step)) {
        re[k | (1 << step)] = re[k] * sx[w];
        re[k] = re[k] * cx[w];
      }
    }
  }
#pragma unroll
  for (int r = 0; r < 64; ++r) im[r] = 0.f;

  run_gates<0>(re, im, wts);

  float a2[64];
#pragma unroll
  for (int r = 0; r < 64; ++r) a2[r] = fmaf(re[r], re[r], im[r] * im[r]);

  expvals<0>(a2, lane, out + bidx * NQ);
}

extern "C" void kernel_launch(void* const* d_in, const int* in_sizes, int n_in,
                              void* d_out, int out_size, void* d_ws, size_t ws_size,
                              hipStream_t stream) {
  const float* x   = (const float*)d_in[0];   // (4096, 12) f32
  const float* wts = (const float*)d_in[1];   // (4, 12) f32
  float* out = (float*)d_out;                 // (4096, 12) f32

  const int batch = in_sizes[0] / NQ;         // 4096
  const int waves_per_block = 4;              // 256 threads
  dim3 grid((batch + waves_per_block - 1) / waves_per_block);
  dim3 block(256);
  qsim_kernel<<<grid, block, 0, stream>>>(x, wts, out);
}

// Round 2
// 155.220 us; speedup vs baseline: 1.1977x; 1.1977x over previous
//
#include <hip/hip_runtime.h>

#define NQ 12
#define NL 4
#define NGATES (NQ * NL)

// ---------------------------------------------------------------------------
// Physical index p = (wave << 11) | (lane << 6..5) | r :
//   bit 11 = wave bit, bits 10..5 = lane bits, bits 4..0 = register bits.
// Logical amplitude psi[y] stored at p = L*y (L linear over GF(2)).
// RX on logical bit b pairs p with p ^ col_b(L); CNOT updates L only;
// <Z_b> sign at p = parity(p & row_b(L^-1)). Qubit w <-> logical bit 11-w.
// Layer-1 RX is folded into the initial product state (state is still a
// product state there), so gates 0..11 are skipped.
// ---------------------------------------------------------------------------
struct Masks { unsigned rx[NGATES]; unsigned z[NQ]; };

constexpr Masks compute_masks() {
  Masks mk{};
  unsigned col[NQ] = {};
  for (int b = 0; b < NQ; ++b) col[b] = 1u << b;
  int g = 0;
  for (int l = 0; l < NL; ++l) {
    for (int w = 0; w < NQ; ++w) mk.rx[g++] = col[NQ - 1 - w];
    for (int i = 0; i < NQ; ++i) {           // ring CNOT(i, (i+1)%12)
      int cb = NQ - 1 - i;
      int tb = NQ - 1 - ((i + 1) % NQ);
      col[cb] ^= col[tb];
    }
  }
  unsigned A[NQ] = {}, Inv[NQ] = {};
  for (int i = 0; i < NQ; ++i) {
    unsigned rowv = 0;
    for (int j = 0; j < NQ; ++j) rowv |= ((col[j] >> i) & 1u) << j;
    A[i] = rowv;
    Inv[i] = 1u << i;
  }
  for (int c = 0; c < NQ; ++c) {
    int piv = c;
    while (((A[piv] >> c) & 1u) == 0u) ++piv;
    unsigned ta = A[piv]; A[piv] = A[c]; A[c] = ta;
    unsigned ti = Inv[piv]; Inv[piv] = Inv[c]; Inv[c] = ti;
    for (int r = 0; r < NQ; ++r)
      if (r != c && ((A[r] >> c) & 1u)) { A[r] ^= A[c]; Inv[r] ^= Inv[c]; }
  }
  for (int w = 0; w < NQ; ++w) mk.z[w] = Inv[NQ - 1 - w];
  return mk;
}

constexpr Masks MK = compute_masks();

__device__ __forceinline__ float shflx(float v, int m) { return __shfl_xor(v, m, 64); }

// Cross-wave exchange, one 8-register chunk. Alternating LDS buffers (CH&1)
// allow a single barrier per chunk: a writer reaches the barrier of chunk
// c+1 only after all readers of chunk c (same buffer used again at c+2) have
// finished their reads.
template <int CH, int ML, int MR>
__device__ __forceinline__ void xchg_chunk(float (&re)[32], float (&im)[32],
                                           float c, float s, float2* xbuf, int tid) {
  static_assert(MR < 8, "partner register must stay within chunk");
  float2* buf = xbuf + (CH & 1) * (8 * 128);
#pragma unroll
  for (int k = 0; k < 8; ++k)
    buf[k * 128 + tid] = make_float2(re[CH * 8 + k], im[CH * 8 + k]);
  __syncthreads();
  const int ptid = tid ^ (64 | ML);
  float2 pv[8];
#pragma unroll
  for (int k = 0; k < 8; ++k) pv[k] = buf[(k ^ MR) * 128 + ptid];
#pragma unroll
  for (int k = 0; k < 8; ++k) {
    const int r = CH * 8 + k;
    float ar = re[r], ai = im[r];
    re[r] = fmaf(s, pv[k].y, c * ar);
    im[r] = fmaf(-s, pv[k].x, c * ai);
  }
}

template <int G>
__device__ __forceinline__ void apply_gate(float (&re)[32], float (&im)[32],
                                           float c, float s, float2* xbuf, int tid) {
  constexpr unsigned m = MK.rx[G];
  constexpr int mw = (int)((m >> 11) & 1u);
  constexpr int ml = (int)((m >> 5) & 63u);
  constexpr int mr = (int)(m & 31u);
  if constexpr (mw) {
    xchg_chunk<0, ml, mr>(re, im, c, s, xbuf, tid);
    xchg_chunk<1, ml, mr>(re, im, c, s, xbuf, tid);
    xchg_chunk<2, ml, mr>(re, im, c, s, xbuf, tid);
    xchg_chunk<3, ml, mr>(re, im, c, s, xbuf, tid);
  } else if constexpr (ml == 0) {
    // in-register pairing
#pragma unroll
    for (int r = 0; r < 32; ++r) {
      const int r2 = r ^ mr;
      if (r < r2) {
        float ar = re[r], ai = im[r], br = re[r2], bi = im[r2];
        re[r]  = fmaf(s, bi, c * ar);
        im[r]  = fmaf(-s, br, c * ai);
        re[r2] = fmaf(s, ai, c * br);
        im[r2] = fmaf(-s, ar, c * bi);
      }
    }
  } else if constexpr (mr == 0) {
    // pure cross-lane
#pragma unroll
    for (int r = 0; r < 32; ++r) {
      float pr_ = shflx(re[r], ml);
      float pi_ = shflx(im[r], ml);
      re[r] = fmaf(s, pi_, c * re[r]);
      im[r] = fmaf(-s, pr_, c * im[r]);
    }
  } else {
    // mixed: partner is register r^mr on lane^ml
#pragma unroll
    for (int r = 0; r < 32; ++r) {
      const int r2 = r ^ mr;
      if (r < r2) {
        float p1r = shflx(re[r2], ml);
        float p1i = shflx(im[r2], ml);
        float p2r = shflx(re[r], ml);
        float p2i = shflx(im[r], ml);
        re[r]  = fmaf(s, p1i, c * re[r]);
        im[r]  = fmaf(-s, p1r, c * im[r]);
        re[r2] = fmaf(s, p2i, c * re[r2]);
        im[r2] = fmaf(-s, p2r, c * im[r2]);
      }
    }
  }
}

template <int G>
__device__ __forceinline__ void run_gates(float (&re)[32], float (&im)[32],
                                          const float* __restrict__ wts,
                                          float2* xbuf, int tid) {
  if constexpr (G < NGATES) {
    float s, c;
    __sincosf(wts[G] * 0.5f, &s, &c);
    apply_gate<G>(re, im, c, s, xbuf, tid);
    run_gates<G + 1>(re, im, wts, xbuf, tid);
  }
}

template <int W>
__device__ __forceinline__ void expvals(const float (&a2)[32], int lane, int wv,
                                        float* zb) {
  if constexpr (W < NQ) {
    constexpr unsigned zm = MK.z[W];
    constexpr int zr = (int)(zm & 31u);
    constexpr int zl = (int)((zm >> 5) & 63u);
    constexpr int zw = (int)((zm >> 11) & 1u);
    float acc = 0.f;
#pragma unroll
    for (int r = 0; r < 32; ++r) {
      if (__builtin_popcount((unsigned)(r & zr)) & 1) acc -= a2[r];
      else                                            acc += a2[r];
    }
    if (__popc(lane & zl) & 1) acc = -acc;
    if constexpr (zw) { if (wv) acc = -acc; }
#pragma unroll
    for (int off = 32; off >= 1; off >>= 1) acc += shflx(acc, off);
    if (lane == 0) zb[wv * NQ + W] = acc;
    expvals<W + 1>(a2, lane, wv, zb);
  }
}

__global__ __launch_bounds__(128, 4) void qsim_kernel(
    const float* __restrict__ x, const float* __restrict__ wts,
    float* __restrict__ out) {
  __shared__ float2 xbuf[2 * 8 * 128];   // 16 KiB exchange double-buffer
  __shared__ float zb[2 * NQ];

  const int bidx = blockIdx.x;           // one batch element per 128-thr block
  const int tid  = threadIdx.x;
  const int lane = tid & 63;
  const int wv   = tid >> 6;

  const float4* xv = reinterpret_cast<const float4*>(x + bidx * NQ);
  float4 q0 = xv[0], q1 = xv[1], q2 = xv[2];
  const float xa[NQ] = {q0.x, q0.y, q0.z, q0.w, q1.x, q1.y, q1.z, q1.w,
                        q2.x, q2.y, q2.z, q2.w};

  // Per-qubit factor after RY(x_w) then layer-1 RX(wts[w]):
  //   bit=0: (c*cy, -s*sy)   bit=1: (c*sy, -s*cy)
  // wave bit = qubit 0; lane bit (6-w) = qubit w for w=1..6 — fold into scalar.
  float lr, li;
  {
    float sy, cy, s, c;
    __sincosf(xa[0] * 0.5f, &sy, &cy);
    __sincosf(wts[0] * 0.5f, &s, &c);
    lr = wv ? c * sy : c * cy;
    li = wv ? -s * cy : -s * sy;
#pragma unroll
    for (int w = 1; w <= 6; ++w) {
      __sincosf(xa[w] * 0.5f, &sy, &cy);
      __sincosf(wts[w] * 0.5f, &s, &c);
      const int b = (lane >> (6 - w)) & 1;
      float gr = b ? c * sy : c * cy;
      float gi = b ? -s * cy : -s * sy;
      float nr = lr * gr - li * gi;
      float ni = lr * gi + li * gr;
      lr = nr; li = ni;
    }
  }

  // reg bit j = qubit 11-j, j=0..4: complex recursive doubling
  float g0r[5], g0i[5], g1r[5], g1i[5];
#pragma unroll
  for (int j = 0; j < 5; ++j) {
    const int w = 11 - j;
    float sy, cy, s, c;
    __sincosf(xa[w] * 0.5f, &sy, &cy);
    __sincosf(wts[w] * 0.5f, &s, &c);
    g0r[j] = c * cy;  g0i[j] = -s * sy;
    g1r[j] = c * sy;  g1i[j] = -s * cy;
  }

  float re[32], im[32];
  re[0] = lr; im[0] = li;
#pragma unroll
  for (int j = 0; j < 5; ++j) {
#pragma unroll
    for (int k = 0; k < 32; ++k) {
      if (k < (1 << j)) {
        float ar = re[k], ai = im[k];
        re[k | (1 << j)] = ar * g1r[j] - ai * g1i[j];
        im[k | (1 << j)] = ar * g1i[j] + ai * g1r[j];
        re[k] = ar * g0r[j] - ai * g0i[j];
        im[k] = ar * g0i[j] + ai * g0r[j];
      }
    }
  }

  run_gates<NQ>(re, im, wts, xbuf, tid);   // layers 2..4 (gates 12..47)

  float a2[32];
#pragma unroll
  for (int r = 0; r < 32; ++r) a2[r] = fmaf(re[r], re[r], im[r] * im[r]);

  expvals<0>(a2, lane, wv, zb);
  __syncthreads();
  if (tid < NQ) out[bidx * NQ + tid] = zb[tid] + zb[NQ + tid];
}

extern "C" void kernel_launch(void* const* d_in, const int* in_sizes, int n_in,
                              void* d_out, int out_size, void* d_ws, size_t ws_size,
                              hipStream_t stream) {
  const float* x   = (const float*)d_in[0];   // (4096, 12) f32
  const float* wts = (const float*)d_in[1];   // (4, 12) f32
  float* out = (float*)d_out;                 // (4096, 12) f32

  const int batch = in_sizes[0] / NQ;         // 4096
  dim3 grid(batch);
  dim3 block(128);
  qsim_kernel<<<grid, block, 0, stream>>>(x, wts, out);
}

// Round 3
// 144.819 us; speedup vs baseline: 1.2837x; 1.0718x over previous
//
#include <hip/hip_runtime.h>

#define NQ 12
#define NL 4
#define NGATES (NQ * NL)

// ---------------------------------------------------------------------------
// Physical index p (12 bits): bit 11 = wave, bits 10..5 = lane, bits 4..0 = reg.
// Logical amplitude psi[y] stored at p = L*y (L linear over GF(2)).
// RX on logical bit b pairs p with p ^ col_b(L); CNOT updates L only;
// <Z_b> sign at p = parity(p & row_b(L^-1)). Qubit w <-> logical bit 11-w.
// Layer-1 RX folded into the initial product state (gates 0..11 skipped).
// Cross-lane exchange: DPP (bits 0-3), permlane16/32_swap (bits 4/5) — all
// VALU-pipe; only the 8 wave-bit gates touch LDS (ds_*_b128, double-buffered).
// ---------------------------------------------------------------------------
struct Masks { unsigned rx[NGATES]; unsigned z[NQ]; };

constexpr Masks compute_masks() {
  Masks mk{};
  unsigned col[NQ] = {};
  for (int b = 0; b < NQ; ++b) col[b] = 1u << b;
  int g = 0;
  for (int l = 0; l < NL; ++l) {
    for (int w = 0; w < NQ; ++w) mk.rx[g++] = col[NQ - 1 - w];
    for (int i = 0; i < NQ; ++i) {           // ring CNOT(i, (i+1)%12)
      int cb = NQ - 1 - i;
      int tb = NQ - 1 - ((i + 1) % NQ);
      col[cb] ^= col[tb];
    }
  }
  unsigned A[NQ] = {}, Inv[NQ] = {};
  for (int i = 0; i < NQ; ++i) {
    unsigned rowv = 0;
    for (int j = 0; j < NQ; ++j) rowv |= ((col[j] >> i) & 1u) << j;
    A[i] = rowv;
    Inv[i] = 1u << i;
  }
  for (int c = 0; c < NQ; ++c) {
    int piv = c;
    while (((A[piv] >> c) & 1u) == 0u) ++piv;
    unsigned ta = A[piv]; A[piv] = A[c]; A[c] = ta;
    unsigned ti = Inv[piv]; Inv[piv] = Inv[c]; Inv[c] = ti;
    for (int r = 0; r < NQ; ++r)
      if (r != c && ((A[r] >> c) & 1u)) { A[r] ^= A[c]; Inv[r] ^= Inv[c]; }
  }
  for (int w = 0; w < NQ; ++w) mk.z[w] = Inv[NQ - 1 - w];
  return mk;
}

constexpr Masks MK = compute_masks();

typedef int v2i __attribute__((ext_vector_type(2)));

template <int CTRL>
__device__ __forceinline__ int dpp_i(int x) {
  return __builtin_amdgcn_update_dpp(x, x, CTRL, 0xf, 0xf, false);
}

// v[lane ^ ML] using VALU-pipe cross-lane ops only (DS fallbacks guarded).
// DPP ctrls: quad_perm xor1=0xB1 xor2=0x4E xor3=0x1B; row_half_mirror
// (xor7)=0x141; row_ror:8 (xor8 within 16)=0x128; row_mirror (xor15)=0x140.
template <int ML>
__device__ __forceinline__ float fetchx(float v) {
  static_assert(ML >= 1 && ML < 64, "lane mask");
  int x = __float_as_int(v);
  constexpr int m4 = ML & 15;
  if constexpr (m4 == 1)       x = dpp_i<0xB1>(x);
  else if constexpr (m4 == 2)  x = dpp_i<0x4E>(x);
  else if constexpr (m4 == 3)  x = dpp_i<0x1B>(x);
  else if constexpr (m4 == 4)  { x = dpp_i<0x141>(x); x = dpp_i<0x1B>(x); }
  else if constexpr (m4 == 5)  { x = dpp_i<0x141>(x); x = dpp_i<0x4E>(x); }
  else if constexpr (m4 == 6)  { x = dpp_i<0x141>(x); x = dpp_i<0xB1>(x); }
  else if constexpr (m4 == 7)  x = dpp_i<0x141>(x);
  else if constexpr (m4 == 8)  x = dpp_i<0x128>(x);
  else if constexpr (m4 == 9)  { x = dpp_i<0x128>(x); x = dpp_i<0xB1>(x); }
  else if constexpr (m4 == 10) { x = dpp_i<0x128>(x); x = dpp_i<0x4E>(x); }
  else if constexpr (m4 == 11) { x = dpp_i<0x128>(x); x = dpp_i<0x1B>(x); }
  else if constexpr (m4 == 12) { x = dpp_i<0x140>(x); x = dpp_i<0x1B>(x); }
  else if constexpr (m4 == 13) { x = dpp_i<0x140>(x); x = dpp_i<0x4E>(x); }
  else if constexpr (m4 == 14) { x = dpp_i<0x140>(x); x = dpp_i<0xB1>(x); }
  else if constexpr (m4 == 15) x = dpp_i<0x140>(x);
  if constexpr (ML & 16) {
#if __has_builtin(__builtin_amdgcn_permlane16_swap)
    v2i r = __builtin_amdgcn_permlane16_swap(x, x, false, false);
    x = (threadIdx.x & 16) ? r.x : r.y;
#else
    x = __builtin_amdgcn_ds_swizzle(x, (16 << 10) | 31);  // xor16 in 32-group
#endif
  }
  if constexpr (ML & 32) {
#if __has_builtin(__builtin_amdgcn_permlane32_swap)
    v2i r = __builtin_amdgcn_permlane32_swap(x, x, false, false);
    x = (threadIdx.x & 32) ? r.x : r.y;
#else
    int a = __shfl_xor(x, 32, 64); x = a;
#endif
  }
  return __int_as_float(x);
}

// Cross-wave exchange, one 8-reg chunk packed as 4 float4 (ds_*_b128).
// Alternating buffers allow a single barrier per chunk (see proof in r2).
template <int CH, int ML, int MR>
__device__ __forceinline__ void xchg_chunk(float (&re)[32], float (&im)[32],
                                           float c, float s, float4* xbuf, int tid) {
  static_assert(MR < 8, "partner register must stay within chunk");
  float4* buf = xbuf + (CH & 1) * (4 * 128);
  constexpr int base = CH * 8;
#pragma unroll
  for (int j = 0; j < 4; ++j)
    buf[j * 128 + tid] = make_float4(re[base + 2 * j], im[base + 2 * j],
                                     re[base + 2 * j + 1], im[base + 2 * j + 1]);
  __syncthreads();
  const int ptid = tid ^ (64 | ML);
  float4 g[4];
#pragma unroll
  for (int j = 0; j < 4; ++j) g[j] = buf[(j ^ (MR >> 1)) * 128 + ptid];
#pragma unroll
  for (int j = 0; j < 4; ++j) {
    float pr0, pi0, pr1, pi1;
    if constexpr (MR & 1) { pr0 = g[j].z; pi0 = g[j].w; pr1 = g[j].x; pi1 = g[j].y; }
    else                  { pr0 = g[j].x; pi0 = g[j].y; pr1 = g[j].z; pi1 = g[j].w; }
    const int r0 = base + 2 * j, r1 = r0 + 1;
    re[r0] = fmaf(s, pi0, c * re[r0]);
    im[r0] = fmaf(-s, pr0, c * im[r0]);
    re[r1] = fmaf(s, pi1, c * re[r1]);
    im[r1] = fmaf(-s, pr1, c * im[r1]);
  }
}

template <int G>
__device__ __forceinline__ void apply_gate(float (&re)[32], float (&im)[32],
                                           float c, float s, float4* xbuf, int tid) {
  constexpr unsigned m = MK.rx[G];
  constexpr int mw = (int)((m >> 11) & 1u);
  constexpr int ml = (int)((m >> 5) & 63u);
  constexpr int mr = (int)(m & 31u);
  if constexpr (mw) {
    xchg_chunk<0, ml, mr>(re, im, c, s, xbuf, tid);
    xchg_chunk<1, ml, mr>(re, im, c, s, xbuf, tid);
    xchg_chunk<2, ml, mr>(re, im, c, s, xbuf, tid);
    xchg_chunk<3, ml, mr>(re, im, c, s, xbuf, tid);
  } else if constexpr (ml == 0) {
    // in-register pairing
#pragma unroll
    for (int r = 0; r < 32; ++r) {
      const int r2 = r ^ mr;
      if (r < r2) {
        float ar = re[r], ai = im[r], br = re[r2], bi = im[r2];
        re[r]  = fmaf(s, bi, c * ar);
        im[r]  = fmaf(-s, br, c * ai);
        re[r2] = fmaf(s, ai, c * br);
        im[r2] = fmaf(-s, ar, c * bi);
      }
    }
  } else if constexpr (mr == 0) {
    // pure cross-lane: VALU shuffle, fetch-before-write per amplitude
#pragma unroll
    for (int r = 0; r < 32; ++r) {
      float pr_ = fetchx<ml>(re[r]);
      float pi_ = fetchx<ml>(im[r]);
      re[r] = fmaf(s, pi_, c * re[r]);
      im[r] = fmaf(-s, pr_, c * im[r]);
    }
  } else {
    // mixed: partner is register r^mr on lane^ml; buffer fetches per pair
#pragma unroll
    for (int r = 0; r < 32; ++r) {
      const int r2 = r ^ mr;
      if (r < r2) {
        float p1r = fetchx<ml>(re[r2]);
        float p1i = fetchx<ml>(im[r2]);
        float p2r = fetchx<ml>(re[r]);
        float p2i = fetchx<ml>(im[r]);
        re[r]  = fmaf(s, p1i, c * re[r]);
        im[r]  = fmaf(-s, p1r, c * im[r]);
        re[r2] = fmaf(s, p2i, c * re[r2]);
        im[r2] = fmaf(-s, p2r, c * im[r2]);
      }
    }
  }
}

template <int G>
__device__ __forceinline__ void run_gates(float (&re)[32], float (&im)[32],
                                          const float* __restrict__ wts,
                                          float4* xbuf, int tid) {
  if constexpr (G < NGATES) {
    float s, c;
    __sincosf(wts[G] * 0.5f, &s, &c);
    apply_gate<G>(re, im, c, s, xbuf, tid);
    run_gates<G + 1>(re, im, wts, xbuf, tid);
  }
}

template <int W>
__device__ __forceinline__ void expvals(const float (&a2)[32], int lane, int wv,
                                        float* zb) {
  if constexpr (W < NQ) {
    constexpr unsigned zm = MK.z[W];
    constexpr int zr = (int)(zm & 31u);
    constexpr int zl = (int)((zm >> 5) & 63u);
    constexpr int zw = (int)((zm >> 11) & 1u);
    float acc = 0.f;
#pragma unroll
    for (int r = 0; r < 32; ++r) {
      if (__builtin_popcount((unsigned)(r & zr)) & 1) acc -= a2[r];
      else                                            acc += a2[r];
    }
    if (__popc(lane & zl) & 1) acc = -acc;
    if constexpr (zw) { if (wv) acc = -acc; }
    acc += fetchx<32>(acc);
    acc += fetchx<16>(acc);
    acc += fetchx<8>(acc);
    acc += fetchx<4>(acc);
    acc += fetchx<2>(acc);
    acc += fetchx<1>(acc);
    if (lane == 0) zb[wv * NQ + W] = acc;
    expvals<W + 1>(a2, lane, wv, zb);
  }
}

__global__ __attribute__((amdgpu_flat_work_group_size(128, 128),
                          amdgpu_waves_per_eu(4, 4)))
void qsim_kernel(const float* __restrict__ x, const float* __restrict__ wts,
                 float* __restrict__ out) {
  __shared__ float4 xbuf[2 * 4 * 128];   // 16 KiB exchange double-buffer
  __shared__ float zb[2 * NQ];

  const int bidx = blockIdx.x;           // one batch element per 128-thr block
  const int tid  = threadIdx.x;
  const int lane = tid & 63;
  const int wv   = tid >> 6;

  const float4* xv = reinterpret_cast<const float4*>(x + bidx * NQ);
  float4 q0 = xv[0], q1 = xv[1], q2 = xv[2];
  const float xa[NQ] = {q0.x, q0.y, q0.z, q0.w, q1.x, q1.y, q1.z, q1.w,
                        q2.x, q2.y, q2.z, q2.w};

  // Per-qubit factor after RY(x_w) then layer-1 RX(wts[w]):
  //   bit=0: (c*cy, -s*sy)   bit=1: (c*sy, -s*cy)
  float lr, li;
  {
    float sy, cy, s, c;
    __sincosf(xa[0] * 0.5f, &sy, &cy);
    __sincosf(wts[0] * 0.5f, &s, &c);
    lr = wv ? c * sy : c * cy;
    li = wv ? -s * cy : -s * sy;
#pragma unroll
    for (int w = 1; w <= 6; ++w) {
      __sincosf(xa[w] * 0.5f, &sy, &cy);
      __sincosf(wts[w] * 0.5f, &s, &c);
      const int b = (lane >> (6 - w)) & 1;
      float gr = b ? c * sy : c * cy;
      float gi = b ? -s * cy : -s * sy;
      float nr = lr * gr - li * gi;
      float ni = lr * gi + li * gr;
      lr = nr; li = ni;
    }
  }

  // reg bit j = qubit 11-j, j=0..4: complex recursive doubling
  float g0r[5], g0i[5], g1r[5], g1i[5];
#pragma unroll
  for (int j = 0; j < 5; ++j) {
    const int w = 11 - j;
    float sy, cy, s, c;
    __sincosf(xa[w] * 0.5f, &sy, &cy);
    __sincosf(wts[w] * 0.5f, &s, &c);
    g0r[j] = c * cy;  g0i[j] = -s * sy;
    g1r[j] = c * sy;  g1i[j] = -s * cy;
  }

  float re[32], im[32];
  re[0] = lr; im[0] = li;
#pragma unroll
  for (int j = 0; j < 5; ++j) {
#pragma unroll
    for (int k = 0; k < 32; ++k) {
      if (k < (1 << j)) {
        float ar = re[k], ai = im[k];
        re[k | (1 << j)] = ar * g1r[j] - ai * g1i[j];
        im[k | (1 << j)] = ar * g1i[j] + ai * g1r[j];
        re[k] = ar * g0r[j] - ai * g0i[j];
        im[k] = ar * g0i[j] + ai * g0r[j];
      }
    }
  }

  run_gates<NQ>(re, im, wts, xbuf, tid);   // layers 2..4 (gates 12..47)

  float a2[32];
#pragma unroll
  for (int r = 0; r < 32; ++r) a2[r] = fmaf(re[r], re[r], im[r] * im[r]);

  expvals<0>(a2, lane, wv, zb);
  __syncthreads();
  if (tid < NQ) out[bidx * NQ + tid] = zb[tid] + zb[NQ + tid];
}

extern "C" void kernel_launch(void* const* d_in, const int* in_sizes, int n_in,
                              void* d_out, int out_size, void* d_ws, size_t ws_size,
                              hipStream_t stream) {
  const float* x   = (const float*)d_in[0];   // (4096, 12) f32
  const float* wts = (const float*)d_in[1];   // (4, 12) f32
  float* out = (float*)d_out;                 // (4096, 12) f32

  const int batch = in_sizes[0] / NQ;         // 4096
  dim3 grid(batch);
  dim3 block(128);
  qsim_kernel<<<grid, block, 0, stream>>>(x, wts, out);
}